// Round 1
// baseline (2623.333 us; speedup 1.0000x reference)
//
#include <hip/hip_runtime.h>
#include <math.h>

#define NT 3072
#define DIM 512
#define NH 8
#define DKH 64
#define PKN 8
#define D2 1024
#define NL 3

typedef float4 f4;

#define FMA16(a, b, acc)                                                       \
  acc[0][0] = fmaf(a.x, b.x, acc[0][0]);                                       \
  acc[0][1] = fmaf(a.x, b.y, acc[0][1]);                                       \
  acc[0][2] = fmaf(a.x, b.z, acc[0][2]);                                       \
  acc[0][3] = fmaf(a.x, b.w, acc[0][3]);                                       \
  acc[1][0] = fmaf(a.y, b.x, acc[1][0]);                                       \
  acc[1][1] = fmaf(a.y, b.y, acc[1][1]);                                       \
  acc[1][2] = fmaf(a.y, b.z, acc[1][2]);                                       \
  acc[1][3] = fmaf(a.y, b.w, acc[1][3]);                                       \
  acc[2][0] = fmaf(a.z, b.x, acc[2][0]);                                       \
  acc[2][1] = fmaf(a.z, b.y, acc[2][1]);                                       \
  acc[2][2] = fmaf(a.z, b.z, acc[2][2]);                                       \
  acc[2][3] = fmaf(a.z, b.w, acc[2][3]);                                       \
  acc[3][0] = fmaf(a.w, b.x, acc[3][0]);                                       \
  acc[3][1] = fmaf(a.w, b.y, acc[3][1]);                                       \
  acc[3][2] = fmaf(a.w, b.z, acc[3][2]);                                       \
  acc[3][3] = fmaf(a.w, b.w, acc[3][3]);

__device__ __forceinline__ float wred_sum(float v) {
#pragma unroll
  for (int off = 32; off > 0; off >>= 1) v += __shfl_xor(v, off);
  return v;
}
__device__ __forceinline__ float wred_max(float v) {
#pragma unroll
  for (int off = 32; off > 0; off >>= 1) v = fmaxf(v, __shfl_xor(v, off));
  return v;
}

// ---------------- LayerNorm (one block per row, D=512) ----------------
__global__ __launch_bounds__(256) void ln_kernel(const float* __restrict__ x,
                                                 const float* __restrict__ s,
                                                 const float* __restrict__ b,
                                                 float* __restrict__ out) {
  int row = blockIdx.x;
  const float* xr = x + (size_t)row * DIM;
  int t = threadIdx.x;
  float v0 = xr[t], v1 = xr[t + 256];
  float sum = wred_sum(v0 + v1);
  float sq = wred_sum(v0 * v0 + v1 * v1);
  __shared__ float ss[4], s2[4];
  if ((t & 63) == 0) { ss[t >> 6] = sum; s2[t >> 6] = sq; }
  __syncthreads();
  float tot = ss[0] + ss[1] + ss[2] + ss[3];
  float tot2 = s2[0] + s2[1] + s2[2] + s2[3];
  float mean = tot * (1.0f / DIM);
  float var = tot2 * (1.0f / DIM) - mean * mean;
  float inv = rsqrtf(var + 1e-6f);
  float* orow = out + (size_t)row * DIM;
  orow[t] = (v0 - mean) * inv * s[t] + b[t];
  orow[t + 256] = (v1 - mean) * inv * s[t + 256] + b[t + 256];
}

// ---------------- Generic fused fp32 GEMM: C = act(A@B + bias) + res ------
// A: [M,K] lda;  A_eff = A * mul (elementwise, nullable)
// B: [K,Nc] ldb; C: [M,Nc] ldc; res added after activation (nullable)
// 64x64 tile, BK=16, 256 threads, 4x4 micro-tile.
template <int ACT>  // 0 none, 1 sigmoid, 2 tanh-gelu
__global__ __launch_bounds__(256) void gemm_kernel(
    const float* __restrict__ A, int lda, const float* __restrict__ B, int ldb,
    const float* __restrict__ bias, const float* __restrict__ mul,
    const float* __restrict__ res, float* __restrict__ C, int ldc, int K) {
  __shared__ float As[16][68];  // [k][i]
  __shared__ float Bs[16][68];  // [k][j]
  int t = threadIdx.x;
  int tx = t & 15, ty = t >> 4;
  int i0 = blockIdx.y * 64, j0 = blockIdx.x * 64;
  int ar = t >> 4, ac = t & 15;
  int br = t >> 6, bc = t & 63;
  float acc[4][4] = {};
  for (int k0 = 0; k0 < K; k0 += 16) {
#pragma unroll
    for (int p = 0; p < 4; ++p) {
      size_t gi = (size_t)(i0 + ar + p * 16) * lda + k0 + ac;
      float a = A[gi];
      if (mul) a *= mul[gi];
      As[ac][ar + p * 16] = a;
    }
#pragma unroll
    for (int p = 0; p < 4; ++p) {
      Bs[br + p * 4][bc] = B[(size_t)(k0 + br + p * 4) * ldb + j0 + bc];
    }
    __syncthreads();
#pragma unroll
    for (int kk = 0; kk < 16; ++kk) {
      f4 a = *(const f4*)&As[kk][ty * 4];
      f4 b = *(const f4*)&Bs[kk][tx * 4];
      FMA16(a, b, acc);
    }
    __syncthreads();
  }
#pragma unroll
  for (int mi = 0; mi < 4; ++mi) {
    int i = i0 + ty * 4 + mi;
    int j = j0 + tx * 4;
    float o[4] = {acc[mi][0], acc[mi][1], acc[mi][2], acc[mi][3]};
    if (bias) {
      f4 bb = *(const f4*)&bias[j];
      o[0] += bb.x; o[1] += bb.y; o[2] += bb.z; o[3] += bb.w;
    }
#pragma unroll
    for (int u = 0; u < 4; ++u) {
      if (ACT == 1) {
        o[u] = 1.0f / (1.0f + expf(-o[u]));
      } else if (ACT == 2) {
        float x = o[u];
        float c = 0.7978845608028654f * (x + 0.044715f * x * x * x);
        o[u] = 0.5f * x * (1.0f + tanhf(c));
      }
    }
    if (res) {
      f4 r = *(const f4*)&res[(size_t)i * ldc + j];
      o[0] += r.x; o[1] += r.y; o[2] += r.z; o[3] += r.w;
    }
    f4 ov = {o[0], o[1], o[2], o[3]};
    *(f4*)&C[(size_t)i * ldc + j] = ov;
  }
}

// ---------------- rq[h,i,p] = dot(q[i, h*64:], rel_k[p,:]) ----------------
__global__ __launch_bounds__(64) void rq_kernel(const float* __restrict__ q,
                                                const float* __restrict__ relk,
                                                float* __restrict__ rq) {
  int i = blockIdx.x;
  int t = threadIdx.x;
  int h = t >> 3, p = t & 7;
  const float* qi = q + (size_t)i * DIM + h * DKH;
  const float* rp = relk + p * DKH;
  float s = 0.f;
#pragma unroll
  for (int d = 0; d < DKH; ++d) s = fmaf(qi[d], rp[d], s);
  rq[((size_t)h * NT + i) * PKN + p] = s;
}

// ---------------- scores: att[h,i,j] = (q_h[i].k_h[j] + rq[h,i,adm[i,j]])/8
__global__ __launch_bounds__(256) void scores_kernel(
    const float* __restrict__ q, const float* __restrict__ k,
    const float* __restrict__ rq, const int* __restrict__ adm,
    float* __restrict__ att) {
  int h = blockIdx.z;
  int i0 = blockIdx.y * 64, j0 = blockIdx.x * 64;
  __shared__ float Qs[64][68];  // [d][i]
  __shared__ float Ks[64][68];  // [d][j]
  int t = threadIdx.x;
  int r = t >> 4, c4 = (t & 15) * 4;
#pragma unroll
  for (int p = 0; p < 4; ++p) {
    f4 qv = *(const f4*)&q[(size_t)(i0 + r + p * 16) * DIM + h * DKH + c4];
    Qs[c4 + 0][r + p * 16] = qv.x;
    Qs[c4 + 1][r + p * 16] = qv.y;
    Qs[c4 + 2][r + p * 16] = qv.z;
    Qs[c4 + 3][r + p * 16] = qv.w;
    f4 kv = *(const f4*)&k[(size_t)(j0 + r + p * 16) * DIM + h * DKH + c4];
    Ks[c4 + 0][r + p * 16] = kv.x;
    Ks[c4 + 1][r + p * 16] = kv.y;
    Ks[c4 + 2][r + p * 16] = kv.z;
    Ks[c4 + 3][r + p * 16] = kv.w;
  }
  __syncthreads();
  int tx = t & 15, ty = t >> 4;
  float acc[4][4] = {};
#pragma unroll 16
  for (int d = 0; d < 64; ++d) {
    f4 a = *(const f4*)&Qs[d][ty * 4];
    f4 b = *(const f4*)&Ks[d][tx * 4];
    FMA16(a, b, acc);
  }
  const float sc = 0.125f;  // 1/sqrt(64)
#pragma unroll
  for (int mi = 0; mi < 4; ++mi) {
    int i = i0 + ty * 4 + mi;
    int4 id4 = *(const int4*)&adm[(size_t)i * NT + j0 + tx * 4];
    const float* rqr = rq + ((size_t)h * NT + i) * PKN;
    f4 o;
    o.x = (acc[mi][0] + rqr[id4.x]) * sc;
    o.y = (acc[mi][1] + rqr[id4.y]) * sc;
    o.z = (acc[mi][2] + rqr[id4.z]) * sc;
    o.w = (acc[mi][3] + rqr[id4.w]) * sc;
    *(f4*)&att[((size_t)h * NT + i) * NT + j0 + tx * 4] = o;
  }
}

// ---------------- softmax in place over rows of att [H,N,N] --------------
__global__ __launch_bounds__(256) void softmax_kernel(float* __restrict__ att) {
  size_t base = ((size_t)blockIdx.y * NT + blockIdx.x) * NT;
  int t = threadIdx.x;
  f4 v[3];
  float mx = -1e30f;
#pragma unroll
  for (int u = 0; u < 3; ++u) {
    v[u] = *(const f4*)&att[base + u * 1024 + t * 4];
    mx = fmaxf(mx, fmaxf(fmaxf(v[u].x, v[u].y), fmaxf(v[u].z, v[u].w)));
  }
  mx = wred_max(mx);
  __shared__ float sm[4];
  if ((t & 63) == 0) sm[t >> 6] = mx;
  __syncthreads();
  mx = fmaxf(fmaxf(sm[0], sm[1]), fmaxf(sm[2], sm[3]));
  float sum = 0.f;
#pragma unroll
  for (int u = 0; u < 3; ++u) {
    v[u].x = expf(v[u].x - mx);
    v[u].y = expf(v[u].y - mx);
    v[u].z = expf(v[u].z - mx);
    v[u].w = expf(v[u].w - mx);
    sum += v[u].x + v[u].y + v[u].z + v[u].w;
  }
  sum = wred_sum(sum);
  __syncthreads();
  if ((t & 63) == 0) sm[t >> 6] = sum;
  __syncthreads();
  float inv = 1.0f / (sm[0] + sm[1] + sm[2] + sm[3]);
#pragma unroll
  for (int u = 0; u < 3; ++u) {
    v[u].x *= inv; v[u].y *= inv; v[u].z *= inv; v[u].w *= inv;
    *(f4*)&att[base + u * 1024 + t * 4] = v[u];
  }
}

// ---------------- PV: av[i, h*64+d] = sum_j att[h,i,j] * v[j, h*64+d] -----
__global__ __launch_bounds__(256) void pv_kernel(const float* __restrict__ att,
                                                 const float* __restrict__ v,
                                                 float* __restrict__ av) {
  int h = blockIdx.y;
  int i0 = blockIdx.x * 64;
  const float* atth = att + (size_t)h * NT * NT;
  __shared__ float As[32][68];  // [k][i]
  __shared__ float Bs[32][68];  // [k][d]
  int t = threadIdx.x;
  int tx = t & 15, ty = t >> 4;
  int ar = t >> 3, ac4 = (t & 7) * 4;
  int brr = t >> 4, bc4 = (t & 15) * 4;
  float acc[4][4] = {};
  for (int k0 = 0; k0 < NT; k0 += 32) {
#pragma unroll
    for (int p = 0; p < 2; ++p) {
      f4 a = *(const f4*)&atth[(size_t)(i0 + ar + p * 32) * NT + k0 + ac4];
      As[ac4 + 0][ar + p * 32] = a.x;
      As[ac4 + 1][ar + p * 32] = a.y;
      As[ac4 + 2][ar + p * 32] = a.z;
      As[ac4 + 3][ar + p * 32] = a.w;
      f4 b = *(const f4*)&v[(size_t)(k0 + brr + p * 16) * DIM + h * DKH + bc4];
      *(f4*)&Bs[brr + p * 16][bc4] = b;
    }
    __syncthreads();
#pragma unroll
    for (int kk = 0; kk < 32; ++kk) {
      f4 a = *(const f4*)&As[kk][ty * 4];
      f4 b = *(const f4*)&Bs[kk][tx * 4];
      FMA16(a, b, acc);
    }
    __syncthreads();
  }
#pragma unroll
  for (int mi = 0; mi < 4; ++mi) {
    f4 o = {acc[mi][0], acc[mi][1], acc[mi][2], acc[mi][3]};
    *(f4*)&av[(size_t)(i0 + ty * 4 + mi) * DIM + h * DKH + tx * 4] = o;
  }
}

extern "C" void kernel_launch(void* const* d_in, const int* in_sizes, int n_in,
                              void* d_out, int out_size, void* d_ws,
                              size_t ws_size, hipStream_t stream) {
  const float* x_in = (const float*)d_in[0];
  const int* adm = (const int*)d_in[1];
  const float* ln_att_s = (const float*)d_in[2];
  const float* ln_att_b = (const float*)d_in[3];
  const float* Wq = (const float*)d_in[4];
  const float* Wk = (const float*)d_in[5];
  const float* Wv = (const float*)d_in[6];
  const float* rel_k = (const float*)d_in[7];
  const float* Wg = (const float*)d_in[8];
  const float* bg = (const float*)d_in[9];
  const float* Wo = (const float*)d_in[10];
  const float* bo = (const float*)d_in[11];
  const float* ln_ff_s = (const float*)d_in[12];
  const float* ln_ff_b = (const float*)d_in[13];
  const float* W1 = (const float*)d_in[14];
  const float* b1 = (const float*)d_in[15];
  const float* W2 = (const float*)d_in[16];
  const float* b2 = (const float*)d_in[17];
  float* out = (float*)d_out;

  const size_t ND = (size_t)NT * DIM;
  float* ws = (float*)d_ws;
  // Aliased workspace layout (38.5 MB):
  float* x_cur = ws;           // residual stream
  float* xn = ws + ND;         // ln_att out; later reused as yn
  float* q = ws + 2 * ND;      // later reused as y
  float* k = ws + 3 * ND;      // later reused as av
  float* v = ws + 4 * ND;      // [4ND,6ND) later reused as h1 (N x 2D)
  float* gt = ws + 5 * ND;
  float* h1 = ws + 4 * ND;
  float* rqb = ws + 6 * ND;    // H*N*PK

  hipMemcpyAsync(x_cur, x_in, ND * sizeof(float), hipMemcpyDeviceToDevice,
                 stream);

  dim3 g512(DIM / 64, NT / 64);
  dim3 g1024(D2 / 64, NT / 64);

  for (int n = 0; n < NL; ++n) {
    float* att = out + ND + (size_t)n * NH * NT * NT;

    ln_kernel<<<NT, 256, 0, stream>>>(x_cur, ln_att_s + n * DIM,
                                      ln_att_b + n * DIM, xn);
    gemm_kernel<0><<<g512, 256, 0, stream>>>(xn, DIM, Wq + (size_t)n * DIM * DIM,
                                             DIM, nullptr, nullptr, nullptr, q,
                                             DIM, DIM);
    gemm_kernel<0><<<g512, 256, 0, stream>>>(xn, DIM, Wk + (size_t)n * DIM * DIM,
                                             DIM, nullptr, nullptr, nullptr, k,
                                             DIM, DIM);
    gemm_kernel<0><<<g512, 256, 0, stream>>>(xn, DIM, Wv + (size_t)n * DIM * DIM,
                                             DIM, nullptr, nullptr, nullptr, v,
                                             DIM, DIM);
    gemm_kernel<1><<<g512, 256, 0, stream>>>(xn, DIM, Wg + (size_t)n * DIM * DIM,
                                             DIM, bg + n * DIM, nullptr, nullptr,
                                             gt, DIM, DIM);
    rq_kernel<<<NT, 64, 0, stream>>>(q, rel_k + n * PKN * DKH, rqb);
    scores_kernel<<<dim3(NT / 64, NT / 64, NH), 256, 0, stream>>>(q, k, rqb,
                                                                  adm, att);
    softmax_kernel<<<dim3(NT, NH), 256, 0, stream>>>(att);
    pv_kernel<<<dim3(NT / 64, NH), 256, 0, stream>>>(att, v, k /*av*/);
    // y = x + (av * gate) @ Wo + bo
    gemm_kernel<0><<<g512, 256, 0, stream>>>(k /*av*/, DIM,
                                             Wo + (size_t)n * DIM * DIM, DIM,
                                             bo + n * DIM, gt, x_cur, q /*y*/,
                                             DIM, DIM);
    ln_kernel<<<NT, 256, 0, stream>>>(q /*y*/, ln_ff_s + n * DIM,
                                      ln_ff_b + n * DIM, xn /*yn*/);
    gemm_kernel<2><<<g1024, 256, 0, stream>>>(xn, DIM,
                                              W1 + (size_t)n * DIM * D2, D2,
                                              b1 + n * D2, nullptr, nullptr, h1,
                                              D2, DIM);
    // x = x + h1 @ W2 + b2
    gemm_kernel<0><<<g512, 256, 0, stream>>>(h1, D2, W2 + (size_t)n * D2 * DIM,
                                             DIM, b2 + n * DIM, nullptr, x_cur,
                                             x_cur, DIM, D2);
  }
  hipMemcpyAsync(out, x_cur, ND * sizeof(float), hipMemcpyDeviceToDevice,
                 stream);
}

// Round 2
// 1198.943 us; speedup vs baseline: 2.1880x; 2.1880x over previous
//
#include <hip/hip_runtime.h>
#include <math.h>

#define NT 3072
#define DIM 512
#define NH 8
#define DKH 64
#define PKN 8
#define D2 1024
#define NL 3

typedef float4 f4;
typedef unsigned short ushort_t;
typedef unsigned char uchar_t;
typedef __attribute__((ext_vector_type(8))) short s8x;
typedef __attribute__((ext_vector_type(4))) float fx4;

#define MFMA(a, b, c) __builtin_amdgcn_mfma_f32_16x16x32_bf16(a, b, c, 0, 0, 0)

__device__ __forceinline__ float b2f(ushort_t u) {
  union { unsigned int x; float f; } c;
  c.x = (unsigned int)u << 16;
  return c.f;
}
__device__ __forceinline__ ushort_t f2b(float f) {
  union { float f; unsigned int x; } c;
  c.f = f;
  unsigned int r = (c.x + 0x7FFFu + ((c.x >> 16) & 1u)) >> 16;
  return (ushort_t)r;
}

__device__ __forceinline__ float wred_sum(float v) {
#pragma unroll
  for (int off = 32; off > 0; off >>= 1) v += __shfl_xor(v, off);
  return v;
}

// ---------------- LayerNorm -> bf16 out (one block per row, D=512) --------
__global__ __launch_bounds__(256) void ln_bf16_kernel(
    const float* __restrict__ x, const float* __restrict__ s,
    const float* __restrict__ b, ushort_t* __restrict__ out) {
  int row = blockIdx.x;
  const float* xr = x + (size_t)row * DIM;
  int t = threadIdx.x;
  float v0 = xr[t], v1 = xr[t + 256];
  float sum = wred_sum(v0 + v1);
  float sq = wred_sum(v0 * v0 + v1 * v1);
  __shared__ float ss[4], s2[4];
  if ((t & 63) == 0) { ss[t >> 6] = sum; s2[t >> 6] = sq; }
  __syncthreads();
  float tot = ss[0] + ss[1] + ss[2] + ss[3];
  float tot2 = s2[0] + s2[1] + s2[2] + s2[3];
  float mean = tot * (1.0f / DIM);
  float var = tot2 * (1.0f / DIM) - mean * mean;
  float inv = rsqrtf(var + 1e-6f);
  ushort_t* orow = out + (size_t)row * DIM;
  orow[t] = f2b((v0 - mean) * inv * s[t] + b[t]);
  orow[t + 256] = f2b((v1 - mean) * inv * s[t + 256] + b[t + 256]);
}

// ---------------- transpose + fp32->bf16 weight conversion ---------------
// W: [K, Nc] fp32 row-major -> Wt: [Nc, K] bf16 row-major
__global__ __launch_bounds__(256) void tconv_kernel(const float* __restrict__ W,
                                                    ushort_t* __restrict__ Wt,
                                                    int K, int Nc) {
  __shared__ float Ls[64][65];
  int t = threadIdx.x;
  int n0 = blockIdx.x * 64, k0 = blockIdx.y * 64;
  int rr = t >> 4, cc = (t & 15) * 4;
#pragma unroll
  for (int p = 0; p < 4; ++p) {
    f4 v = *(const f4*)&W[(size_t)(k0 + rr + p * 16) * Nc + n0 + cc];
    Ls[rr + p * 16][cc + 0] = v.x;
    Ls[rr + p * 16][cc + 1] = v.y;
    Ls[rr + p * 16][cc + 2] = v.z;
    Ls[rr + p * 16][cc + 3] = v.w;
  }
  __syncthreads();
  int nr = t >> 2, kc = (t & 3) * 16;
  ushort_t tmp[16];
#pragma unroll
  for (int e = 0; e < 16; ++e) tmp[e] = f2b(Ls[kc + e][nr]);
  ushort_t* dst = &Wt[(size_t)(n0 + nr) * K + k0 + kc];
  *(uint4*)dst = *(uint4*)&tmp[0];
  *(uint4*)(dst + 8) = *(uint4*)&tmp[8];
}

// ---------------- adm int32 -> int8 --------------------------------------
__global__ __launch_bounds__(256) void adm8_kernel(const int* __restrict__ adm,
                                                   uchar_t* __restrict__ out) {
  size_t i = ((size_t)blockIdx.x * 256 + threadIdx.x) * 4;
  int4 v = *(const int4*)&adm[i];
  unsigned int b = (unsigned)(v.x & 255) | ((unsigned)(v.y & 255) << 8) |
                   ((unsigned)(v.z & 255) << 16) | ((unsigned)(v.w & 255) << 24);
  *(unsigned int*)&out[i] = b;
}

// ---------------- rq[i, h*8+p] = dot(q_bf16[i, h*64:], rel_k[p,:]) -------
__global__ __launch_bounds__(64) void rq_kernel(const ushort_t* __restrict__ q,
                                                const float* __restrict__ relk,
                                                float* __restrict__ rq) {
  int i = blockIdx.x;
  int t = threadIdx.x;
  int h = t >> 3, p = t & 7;
  const ushort_t* qi = q + (size_t)i * DIM + h * DKH;
  const float* rp = relk + p * DKH;
  float s = 0.f;
#pragma unroll
  for (int d = 0; d < DKH; ++d) s = fmaf(b2f(qi[d]), rp[d], s);
  rq[(size_t)i * 64 + h * 8 + p] = s;
}

// ---------------- bf16 MFMA GEMM: C = act(scale*(A.*mul)@Bt^T + bias)+res
// A: [M,K] bf16 row-major; Bt: [Nc,K] bf16 (B transposed); tile 64x64, BK=32.
template <int ACT, bool OBF>  // ACT: 0 none, 1 sigmoid, 2 tanh-gelu
__global__ __launch_bounds__(256) void gemm_bf16(
    const ushort_t* __restrict__ A, const ushort_t* __restrict__ mul,
    const ushort_t* __restrict__ Bt, const float* __restrict__ bias,
    const float* __restrict__ res, void* __restrict__ Cp, int K, int ldc,
    float scale) {
  __shared__ __align__(16) ushort_t As[2048];
  __shared__ __align__(16) ushort_t Bs[2048];
  int t = threadIdx.x;
  int i0 = blockIdx.y * 64, j0 = blockIdx.x * 64;
  int w = t >> 6, l = t & 63;
  int wm = w >> 1, wn = w & 1;
  int lr = l >> 4, lc = l & 15;
  int fo = lr * 16 + (lc ^ (lr << 2));  // frag addr16 within 64-cell block
  // A staging: thread t -> row am, kgroup akg
  int am = t >> 2, akg = t & 3;
  int aoff = ((am >> 4) * 4 + akg) * 16 + ((am & 15) ^ (akg << 2));
  const ushort_t* Aptr = A + (size_t)(i0 + am) * K + akg * 8;
  const ushort_t* Mptr = mul ? mul + (size_t)(i0 + am) * K + akg * 8 : nullptr;
  // B staging: thread t -> col bc, kgroup w
  int bc = l, bkg = w;
  int boff = ((bc >> 4) * 4 + bkg) * 16 + ((bc & 15) ^ (bkg << 2));
  const ushort_t* Bptr = Bt + (size_t)(j0 + bc) * K + bkg * 8;

  fx4 acc[2][2] = {};
  for (int k0 = 0; k0 < K; k0 += 32) {
    uint4 a = *(const uint4*)(Aptr + k0);
    if (mul) {
      uint4 m = *(const uint4*)(Mptr + k0);
      ushort_t* ap = (ushort_t*)&a;
      const ushort_t* mp = (const ushort_t*)&m;
#pragma unroll
      for (int e = 0; e < 8; ++e) ap[e] = f2b(b2f(ap[e]) * b2f(mp[e]));
    }
    *(uint4*)&As[aoff * 8] = a;
    *(uint4*)&Bs[boff * 8] = *(const uint4*)(Bptr + k0);
    __syncthreads();
    s8x a0 = *(const s8x*)&As[((wm * 2 + 0) * 64 + fo) * 8];
    s8x a1 = *(const s8x*)&As[((wm * 2 + 1) * 64 + fo) * 8];
    s8x b0 = *(const s8x*)&Bs[((wn * 2 + 0) * 64 + fo) * 8];
    s8x b1 = *(const s8x*)&Bs[((wn * 2 + 1) * 64 + fo) * 8];
    acc[0][0] = MFMA(a0, b0, acc[0][0]);
    acc[0][1] = MFMA(a0, b1, acc[0][1]);
    acc[1][0] = MFMA(a1, b0, acc[1][0]);
    acc[1][1] = MFMA(a1, b1, acc[1][1]);
    __syncthreads();
  }
#pragma unroll
  for (int ms = 0; ms < 2; ++ms) {
#pragma unroll
    for (int ns = 0; ns < 2; ++ns) {
#pragma unroll
      for (int r = 0; r < 4; ++r) {
        int i = i0 + (wm * 2 + ms) * 16 + lr * 4 + r;
        int j = j0 + (wn * 2 + ns) * 16 + lc;
        float o = acc[ms][ns][r] * scale;
        if (bias) o += bias[j];
        if (ACT == 1) {
          o = 1.0f / (1.0f + __expf(-o));
        } else if (ACT == 2) {
          float xx = o;
          float c = 0.7978845608028654f * (xx + 0.044715f * xx * xx * xx);
          o = 0.5f * xx * (1.0f + tanhf(c));
        }
        if (res) o += res[(size_t)i * ldc + j];
        if (OBF)
          ((ushort_t*)Cp)[(size_t)i * ldc + j] = f2b(o);
        else
          ((float*)Cp)[(size_t)i * ldc + j] = o;
      }
    }
  }
}

// ---------------- fused attention: scores + rel-gather + softmax + PV -----
// block: (i-block of 64 rows, head h). Two passes over j; writes normalized
// P (fp32) to att and O (bf16) to av.
__global__ __launch_bounds__(256) void attn_kernel(
    const ushort_t* __restrict__ qb, const ushort_t* __restrict__ kb,
    const ushort_t* __restrict__ vb, const float* __restrict__ rqb,
    const uchar_t* __restrict__ adm8, float* __restrict__ att,
    ushort_t* __restrict__ av) {
  int h = blockIdx.y;
  int i0 = blockIdx.x * 64;
  __shared__ __align__(16) ushort_t Qs[4096];
  __shared__ __align__(16) ushort_t Ks[4096];
  __shared__ __align__(16) ushort_t Vs[4096];
  __shared__ __align__(16) ushort_t Ps[4096];
  __shared__ __align__(16) uchar_t adms[4096];
  __shared__ float rqs[64][8];
  int t = threadIdx.x, w = t >> 6, l = t & 63;
  int lr = l >> 4, lc = l & 15;
  int fo = lr * 16 + (lc ^ (lr << 2));
  // stage Q (both k-steps) + rq rows
  {
    int am = t >> 2, akg = t & 3;
    int aoff = ((am >> 4) * 4 + akg) * 16 + ((am & 15) ^ (akg << 2));
    const ushort_t* qp = qb + (size_t)(i0 + am) * DIM + h * DKH + akg * 8;
    *(uint4*)&Qs[aoff * 8] = *(const uint4*)qp;
    *(uint4*)&Qs[2048 + aoff * 8] = *(const uint4*)(qp + 32);
  }
  if (t < 64) {
    const float* rp = &rqb[(size_t)(i0 + t) * 64 + h * 8];
    *(f4*)&rqs[t][0] = *(const f4*)rp;
    *(f4*)&rqs[t][4] = *(const f4*)(rp + 4);
  }
  __syncthreads();
  s8x qa0 = *(const s8x*)&Qs[(w * 64 + fo) * 8];
  s8x qa1 = *(const s8x*)&Qs[2048 + (w * 64 + fo) * 8];
  int bc = l, bkg = w;
  int boff = ((bc >> 4) * 4 + bkg) * 16 + ((bc & 15) ^ (bkg << 2));

  float m_run[4] = {-1e30f, -1e30f, -1e30f, -1e30f};
  float l_run[4] = {0.f, 0.f, 0.f, 0.f};

  // ---- pass 1: running max / sum ----
  for (int j0 = 0; j0 < NT; j0 += 64) {
    __syncthreads();
    const ushort_t* kp = kb + (size_t)(j0 + bc) * DIM + h * DKH + bkg * 8;
    *(uint4*)&Ks[boff * 8] = *(const uint4*)kp;
    *(uint4*)&Ks[2048 + boff * 8] = *(const uint4*)(kp + 32);
    *(uint4*)&adms[(t >> 2) * 64 + (t & 3) * 16] =
        *(const uint4*)&adm8[(size_t)(i0 + (t >> 2)) * NT + j0 + (t & 3) * 16];
    __syncthreads();
    fx4 sacc[4] = {};
#pragma unroll
    for (int nb = 0; nb < 4; ++nb) {
      s8x k0f = *(const s8x*)&Ks[(nb * 64 + fo) * 8];
      s8x k1f = *(const s8x*)&Ks[2048 + (nb * 64 + fo) * 8];
      sacc[nb] = MFMA(qa0, k0f, sacc[nb]);
      sacc[nb] = MFMA(qa1, k1f, sacc[nb]);
    }
#pragma unroll
    for (int r = 0; r < 4; ++r) {
      int il = w * 16 + lr * 4 + r;
      float sv[4];
      float tm = -1e30f;
#pragma unroll
      for (int nb = 0; nb < 4; ++nb) {
        sv[nb] = sacc[nb][r] + rqs[il][adms[il * 64 + nb * 16 + lc]];
        tm = fmaxf(tm, sv[nb]);
      }
      tm = fmaxf(tm, __shfl_xor(tm, 1));
      tm = fmaxf(tm, __shfl_xor(tm, 2));
      tm = fmaxf(tm, __shfl_xor(tm, 4));
      tm = fmaxf(tm, __shfl_xor(tm, 8));
      float mn = fmaxf(m_run[r], tm);
      float ssum = 0.f;
#pragma unroll
      for (int nb = 0; nb < 4; ++nb) ssum += __expf(sv[nb] - mn);
      ssum += __shfl_xor(ssum, 1);
      ssum += __shfl_xor(ssum, 2);
      ssum += __shfl_xor(ssum, 4);
      ssum += __shfl_xor(ssum, 8);
      l_run[r] = l_run[r] * __expf(m_run[r] - mn) + ssum;
      m_run[r] = mn;
    }
  }
  float linv[4];
#pragma unroll
  for (int r = 0; r < 4; ++r) linv[r] = 1.0f / l_run[r];

  // ---- pass 2: recompute S, write P, accumulate PV ----
  fx4 oacc[4] = {};
  float* attb = att + ((size_t)h * NT + i0) * NT;
  for (int j0 = 0; j0 < NT; j0 += 64) {
    __syncthreads();
    const ushort_t* kp = kb + (size_t)(j0 + bc) * DIM + h * DKH + bkg * 8;
    *(uint4*)&Ks[boff * 8] = *(const uint4*)kp;
    *(uint4*)&Ks[2048 + boff * 8] = *(const uint4*)(kp + 32);
    *(uint4*)&adms[(t >> 2) * 64 + (t & 3) * 16] =
        *(const uint4*)&adm8[(size_t)(i0 + (t >> 2)) * NT + j0 + (t & 3) * 16];
    // stage V in B-frag layout (strided bf16 gathers, L2-resident)
#pragma unroll
    for (int cpass = 0; cpass < 2; ++cpass) {
      int cid = t + cpass * 256;
      int vks = cid >> 8, rem = cid & 255;
      int nb = rem >> 6, kg = (rem >> 4) & 3, s = rem & 15;
      const ushort_t* vp =
          vb + (size_t)(j0 + vks * 32 + kg * 8) * DIM + h * DKH + nb * 16 + s;
      ushort_t tmp[8];
#pragma unroll
      for (int e = 0; e < 8; ++e) tmp[e] = vp[(size_t)e * DIM];
      *(uint4*)&Vs[vks * 2048 + ((nb * 4 + kg) * 16 + (s ^ (kg << 2))) * 8] =
          *(uint4*)tmp;
    }
    __syncthreads();
    fx4 sacc[4] = {};
#pragma unroll
    for (int nb = 0; nb < 4; ++nb) {
      s8x k0f = *(const s8x*)&Ks[(nb * 64 + fo) * 8];
      s8x k1f = *(const s8x*)&Ks[2048 + (nb * 64 + fo) * 8];
      sacc[nb] = MFMA(qa0, k0f, sacc[nb]);
      sacc[nb] = MFMA(qa1, k1f, sacc[nb]);
    }
#pragma unroll
    for (int r = 0; r < 4; ++r) {
      int il = w * 16 + lr * 4 + r;
      int ir = il & 15;
#pragma unroll
      for (int nb = 0; nb < 4; ++nb) {
        int jl = nb * 16 + lc;
        float sval = sacc[nb][r] + rqs[il][adms[il * 64 + jl]];
        float p = __expf(sval - m_run[r]) * linv[r];
        attb[(size_t)il * NT + j0 + jl] = p;
        int pks = jl >> 5, pkg = (jl >> 3) & 3, pe = jl & 7;
        Ps[pks * 2048 + ((w * 4 + pkg) * 16 + (ir ^ (pkg << 2))) * 8 + pe] =
            f2b(p);
      }
    }
    __syncthreads();
#pragma unroll
    for (int ks = 0; ks < 2; ++ks) {
      s8x pa = *(const s8x*)&Ps[ks * 2048 + (w * 64 + fo) * 8];
#pragma unroll
      for (int nb = 0; nb < 4; ++nb) {
        s8x vf = *(const s8x*)&Vs[ks * 2048 + (nb * 64 + fo) * 8];
        oacc[nb] = MFMA(pa, vf, oacc[nb]);
      }
    }
  }
#pragma unroll
  for (int nb = 0; nb < 4; ++nb)
#pragma unroll
    for (int r = 0; r < 4; ++r)
      av[(size_t)(i0 + w * 16 + lr * 4 + r) * DIM + h * DKH + nb * 16 + lc] =
          f2b(oacc[nb][r]);
}

extern "C" void kernel_launch(void* const* d_in, const int* in_sizes, int n_in,
                              void* d_out, int out_size, void* d_ws,
                              size_t ws_size, hipStream_t stream) {
  const float* x_in = (const float*)d_in[0];
  const int* adm = (const int*)d_in[1];
  const float* ln_att_s = (const float*)d_in[2];
  const float* ln_att_b = (const float*)d_in[3];
  const float* Wq = (const float*)d_in[4];
  const float* Wk = (const float*)d_in[5];
  const float* Wv = (const float*)d_in[6];
  const float* rel_k = (const float*)d_in[7];
  const float* Wg = (const float*)d_in[8];
  const float* bg = (const float*)d_in[9];
  const float* Wo = (const float*)d_in[10];
  const float* bo = (const float*)d_in[11];
  const float* ln_ff_s = (const float*)d_in[12];
  const float* ln_ff_b = (const float*)d_in[13];
  const float* W1 = (const float*)d_in[14];
  const float* b1 = (const float*)d_in[15];
  const float* W2 = (const float*)d_in[16];
  const float* b2 = (const float*)d_in[17];
  float* out = (float*)d_out;

  const size_t ND = (size_t)NT * DIM;
  char* ws = (char*)d_ws;
  // byte-offset workspace layout (~46.4 MB total)
  float* x_cur = (float*)ws;                         // 6.29 MB
  float* y = (float*)(ws + 6291456);                 // 6.29 MB
  ushort_t* qb = (ushort_t*)(ws + 12582912);         // 3.15 MB
  ushort_t* kb = (ushort_t*)(ws + 15728640);         // 3.15 MB
  ushort_t* vb = (ushort_t*)(ws + 18874368);         // 3.15 MB
  ushort_t* gt = (ushort_t*)(ws + 22020096);         // 3.15 MB
  ushort_t* avb = (ushort_t*)(ws + 25165824);        // 3.15 MB
  ushort_t* xnb = (ushort_t*)(ws + 28311552);        // 3.15 MB
  float* rqb = (float*)(ws + 31457280);              // 0.79 MB
  uchar_t* adm8 = (uchar_t*)(ws + 32243712);         // 9.44 MB
  ushort_t* Wt = (ushort_t*)(ws + 41680896);         // 4.72 MB (per-layer)
  ushort_t* h1b = qb;  // FFN hidden [N,2D] bf16 aliases qb+kb (6.29 MB)

  ushort_t* Wtq = Wt;
  ushort_t* Wtk = Wt + 262144;
  ushort_t* Wtv = Wt + 524288;
  ushort_t* Wtg = Wt + 786432;
  ushort_t* Wto = Wt + 1048576;
  ushort_t* Wt1 = Wt + 1310720;  // [1024,512]
  ushort_t* Wt2 = Wt + 1835008;  // [512,1024]

  hipMemcpyAsync(x_cur, x_in, ND * sizeof(float), hipMemcpyDeviceToDevice,
                 stream);
  adm8_kernel<<<(NT * NT) / 1024, 256, 0, stream>>>(adm, adm8);

  dim3 gA(DIM / 64, NT / 64);   // N=512 GEMMs
  dim3 gF1(D2 / 64, NT / 64);   // N=1024 GEMM
  dim3 gT(8, 8);                // 512x512 transpose
  dim3 gT1(16, 8);              // W1: K=512, Nc=1024
  dim3 gT2(8, 16);              // W2: K=1024, Nc=512

  for (int n = 0; n < NL; ++n) {
    float* att = out + ND + (size_t)n * NH * NT * NT;
    size_t wo = (size_t)n * DIM * DIM;

    tconv_kernel<<<gT, 256, 0, stream>>>(Wq + wo, Wtq, DIM, DIM);
    tconv_kernel<<<gT, 256, 0, stream>>>(Wk + wo, Wtk, DIM, DIM);
    tconv_kernel<<<gT, 256, 0, stream>>>(Wv + wo, Wtv, DIM, DIM);
    tconv_kernel<<<gT, 256, 0, stream>>>(Wg + wo, Wtg, DIM, DIM);
    tconv_kernel<<<gT, 256, 0, stream>>>(Wo + wo, Wto, DIM, DIM);
    tconv_kernel<<<gT1, 256, 0, stream>>>(W1 + (size_t)n * DIM * D2, Wt1, DIM,
                                          D2);
    tconv_kernel<<<gT2, 256, 0, stream>>>(W2 + (size_t)n * D2 * DIM, Wt2, D2,
                                          DIM);

    ln_bf16_kernel<<<NT, 256, 0, stream>>>(x_cur, ln_att_s + n * DIM,
                                           ln_att_b + n * DIM, xnb);
    // q scaled by 1/sqrt(DK)=0.125 (propagates into rq correctly)
    gemm_bf16<0, true><<<gA, 256, 0, stream>>>(xnb, nullptr, Wtq, nullptr,
                                               nullptr, qb, DIM, DIM, 0.125f);
    gemm_bf16<0, true><<<gA, 256, 0, stream>>>(xnb, nullptr, Wtk, nullptr,
                                               nullptr, kb, DIM, DIM, 1.0f);
    gemm_bf16<0, true><<<gA, 256, 0, stream>>>(xnb, nullptr, Wtv, nullptr,
                                               nullptr, vb, DIM, DIM, 1.0f);
    gemm_bf16<1, true><<<gA, 256, 0, stream>>>(xnb, nullptr, Wtg, bg + n * DIM,
                                               nullptr, gt, DIM, DIM, 1.0f);
    rq_kernel<<<NT, 64, 0, stream>>>(qb, rel_k + n * PKN * DKH, rqb);
    attn_kernel<<<dim3(NT / 64, NH), 256, 0, stream>>>(qb, kb, vb, rqb, adm8,
                                                       att, avb);
    // y = x + (av*gate)@Wo + bo
    gemm_bf16<0, false><<<gA, 256, 0, stream>>>(avb, gt, Wto, bo + n * DIM,
                                                x_cur, y, DIM, DIM, 1.0f);
    ln_bf16_kernel<<<NT, 256, 0, stream>>>(y, ln_ff_s + n * DIM,
                                           ln_ff_b + n * DIM, xnb);
    gemm_bf16<2, true><<<gF1, 256, 0, stream>>>(xnb, nullptr, Wt1, b1 + n * D2,
                                                nullptr, h1b, DIM, D2, 1.0f);
    gemm_bf16<0, false><<<gA, 256, 0, stream>>>(h1b, nullptr, Wt2, b2 + n * DIM,
                                                x_cur, x_cur, D2, DIM, 1.0f);
  }
  hipMemcpyAsync(out, x_cur, ND * sizeof(float), hipMemcpyDeviceToDevice,
                 stream);
}

// Round 3
// 1136.850 us; speedup vs baseline: 2.3075x; 1.0546x over previous
//
#include <hip/hip_runtime.h>
#include <math.h>

#define NT 3072
#define DIM 512
#define NH 8
#define DKH 64
#define PKN 8
#define D2 1024
#define NL 3
#define QS 2048  // row stride of fused qkvg buffer

typedef float4 f4;
typedef unsigned short ushort_t;
typedef unsigned char uchar_t;
typedef __attribute__((ext_vector_type(8))) short s8x;
typedef __attribute__((ext_vector_type(4))) float fx4;

#define MFMA(a, b, c) __builtin_amdgcn_mfma_f32_16x16x32_bf16(a, b, c, 0, 0, 0)
#define EX2(x) __builtin_amdgcn_exp2f(x)

__device__ __forceinline__ float b2f(ushort_t u) {
  union { unsigned int x; float f; } c;
  c.x = (unsigned int)u << 16;
  return c.f;
}
__device__ __forceinline__ ushort_t f2b(float f) {
  union { float f; unsigned int x; } c;
  c.f = f;
  unsigned int r = (c.x + 0x7FFFu + ((c.x >> 16) & 1u)) >> 16;
  return (ushort_t)r;
}
__device__ __forceinline__ float wred_sum(float v) {
#pragma unroll
  for (int off = 32; off > 0; off >>= 1) v += __shfl_xor(v, off);
  return v;
}
__device__ __forceinline__ void gload16(const ushort_t* g, ushort_t* l) {
  __builtin_amdgcn_global_load_lds(
      (const __attribute__((address_space(1))) unsigned int*)(const void*)g,
      (__attribute__((address_space(3))) unsigned int*)(void*)l, 16, 0, 0);
}

// ---------------- LayerNorm -> bf16 ----------------
__global__ __launch_bounds__(256) void ln_bf16_kernel(
    const float* __restrict__ x, const float* __restrict__ s,
    const float* __restrict__ b, ushort_t* __restrict__ out) {
  int row = blockIdx.x;
  const float* xr = x + (size_t)row * DIM;
  int t = threadIdx.x;
  float v0 = xr[t], v1 = xr[t + 256];
  float sum = wred_sum(v0 + v1);
  float sq = wred_sum(v0 * v0 + v1 * v1);
  __shared__ float ss[4], s2[4];
  if ((t & 63) == 0) { ss[t >> 6] = sum; s2[t >> 6] = sq; }
  __syncthreads();
  float tot = ss[0] + ss[1] + ss[2] + ss[3];
  float tot2 = s2[0] + s2[1] + s2[2] + s2[3];
  float mean = tot * (1.0f / DIM);
  float var = tot2 * (1.0f / DIM) - mean * mean;
  float inv = rsqrtf(var + 1e-6f);
  ushort_t* orow = out + (size_t)row * DIM;
  orow[t] = f2b((v0 - mean) * inv * s[t] + b[t]);
  orow[t + 256] = f2b((v1 - mean) * inv * s[t + 256] + b[t + 256]);
}

// ---------------- fused per-layer weight transpose+convert -------------
__device__ __forceinline__ void tconv_body(const float* __restrict__ W,
                                           ushort_t* __restrict__ Wt, int K,
                                           int Nc, int tx, int ty) {
  __shared__ float Ls[64][65];
  int t = threadIdx.x;
  int n0 = tx * 64, k0 = ty * 64;
  int rr = t >> 4, cc = (t & 15) * 4;
#pragma unroll
  for (int p = 0; p < 4; ++p) {
    f4 v = *(const f4*)&W[(size_t)(k0 + rr + p * 16) * Nc + n0 + cc];
    Ls[rr + p * 16][cc + 0] = v.x;
    Ls[rr + p * 16][cc + 1] = v.y;
    Ls[rr + p * 16][cc + 2] = v.z;
    Ls[rr + p * 16][cc + 3] = v.w;
  }
  __syncthreads();
  int nr = t >> 2, kc = (t & 3) * 16;
  ushort_t tmp[16];
#pragma unroll
  for (int e = 0; e < 16; ++e) tmp[e] = f2b(Ls[kc + e][nr]);
  ushort_t* dst = &Wt[(size_t)(n0 + nr) * K + k0 + kc];
  *(uint4*)dst = *(uint4*)&tmp[0];
  *(uint4*)(dst + 8) = *(uint4*)&tmp[8];
}

__global__ __launch_bounds__(256) void wprep_kernel(
    const float* __restrict__ Wq, const float* __restrict__ Wk,
    const float* __restrict__ Wv, const float* __restrict__ Wg,
    const float* __restrict__ Wo, const float* __restrict__ W1,
    const float* __restrict__ W2, ushort_t* __restrict__ Wt) {
  int bid = blockIdx.x;
  if (bid < 320) {
    int job = bid >> 6, tile = bid & 63;
    const float* src = job == 0 ? Wq : job == 1 ? Wk : job == 2 ? Wv
                       : job == 3 ? Wg : Wo;
    tconv_body(src, Wt + (size_t)job * 262144, 512, 512, tile & 7, tile >> 3);
  } else if (bid < 448) {
    int tile = bid - 320;
    tconv_body(W1, Wt + 1310720, 512, 1024, tile & 15, tile >> 4);
  } else {
    int tile = bid - 448;
    tconv_body(W2, Wt + 1835008, 1024, 512, tile & 7, tile >> 3);
  }
}

// ---------------- adm int32 -> int8 ----------------
__global__ __launch_bounds__(256) void adm8_kernel(const int* __restrict__ adm,
                                                   uchar_t* __restrict__ out) {
  size_t i = ((size_t)blockIdx.x * 256 + threadIdx.x) * 4;
  int4 v = *(const int4*)&adm[i];
  unsigned int b = (unsigned)(v.x & 255) | ((unsigned)(v.y & 255) << 8) |
                   ((unsigned)(v.z & 255) << 16) | ((unsigned)(v.w & 255) << 24);
  *(unsigned int*)&out[i] = b;
}

// ---------------- V transpose per head: vbT[h][d][j] = v[j][h*64+d] ------
__global__ __launch_bounds__(256) void vt_kernel(const ushort_t* __restrict__ v,
                                                 ushort_t* __restrict__ vbT) {
  int jt = blockIdx.x, h = blockIdx.y;
  __shared__ ushort_t L[64][72];
  int t = threadIdx.x;
  int r = t >> 2, c = (t & 3) * 16;
  const ushort_t* src = v + (size_t)(jt * 64 + r) * QS + h * 64 + c;
  *(uint4*)&L[r][c] = *(const uint4*)src;
  *(uint4*)&L[r][c + 8] = *(const uint4*)(src + 8);
  __syncthreads();
  int d = t >> 2, j0 = (t & 3) * 16;
  ushort_t tmp[16];
#pragma unroll
  for (int e = 0; e < 16; ++e) tmp[e] = L[j0 + e][d];
  ushort_t* dst = vbT + (size_t)(h * 64 + d) * NT + jt * 64 + j0;
  *(uint4*)dst = *(uint4*)&tmp[0];
  *(uint4*)(dst + 8) = *(uint4*)&tmp[8];
}

// ---------------- bf16 MFMA GEMM ----------------
// ACT: 0 none, 1 sigmoid, 2 tanh-gelu, 3 fused-QKVG epilogue
template <int ACT, bool OBF>
__global__ __launch_bounds__(256) void gemm_bf16(
    const ushort_t* __restrict__ A, const ushort_t* __restrict__ mul, int ldm,
    const ushort_t* __restrict__ Bt, const float* __restrict__ bias,
    const float* __restrict__ res, void* __restrict__ Cp, int K, int ldc,
    float scale) {
  __shared__ __align__(16) ushort_t As[2048];
  __shared__ __align__(16) ushort_t Bs[2048];
  int t = threadIdx.x;
  int i0 = blockIdx.y * 64, j0 = blockIdx.x * 64;
  int w = t >> 6, l = t & 63;
  int wm = w >> 1, wn = w & 1;
  int lr = l >> 4, lc = l & 15;
  int fo = lr * 16 + (lc ^ (lr << 2));
  int am = t >> 2, akg = t & 3;
  int aoff = ((am >> 4) * 4 + akg) * 16 + ((am & 15) ^ (akg << 2));
  const ushort_t* Aptr = A + (size_t)(i0 + am) * K + akg * 8;
  const ushort_t* Mptr = mul ? mul + (size_t)(i0 + am) * ldm + akg * 8 : nullptr;
  int bc = l, bkg = w;
  int boff = ((bc >> 4) * 4 + bkg) * 16 + ((bc & 15) ^ (bkg << 2));
  const ushort_t* Bptr = Bt + (size_t)(j0 + bc) * K + bkg * 8;

  fx4 acc[2][2] = {};
  for (int k0 = 0; k0 < K; k0 += 32) {
    uint4 a = *(const uint4*)(Aptr + k0);
    if (mul) {
      uint4 m = *(const uint4*)(Mptr + k0);
      ushort_t* ap = (ushort_t*)&a;
      const ushort_t* mp = (const ushort_t*)&m;
#pragma unroll
      for (int e = 0; e < 8; ++e) ap[e] = f2b(b2f(ap[e]) * b2f(mp[e]));
    }
    *(uint4*)&As[aoff * 8] = a;
    *(uint4*)&Bs[boff * 8] = *(const uint4*)(Bptr + k0);
    __syncthreads();
    s8x a0 = *(const s8x*)&As[((wm * 2 + 0) * 64 + fo) * 8];
    s8x a1 = *(const s8x*)&As[((wm * 2 + 1) * 64 + fo) * 8];
    s8x b0 = *(const s8x*)&Bs[((wn * 2 + 0) * 64 + fo) * 8];
    s8x b1 = *(const s8x*)&Bs[((wn * 2 + 1) * 64 + fo) * 8];
    acc[0][0] = MFMA(a0, b0, acc[0][0]);
    acc[0][1] = MFMA(a0, b1, acc[0][1]);
    acc[1][0] = MFMA(a1, b0, acc[1][0]);
    acc[1][1] = MFMA(a1, b1, acc[1][1]);
    __syncthreads();
  }
#pragma unroll
  for (int ms = 0; ms < 2; ++ms) {
#pragma unroll
    for (int ns = 0; ns < 2; ++ns) {
#pragma unroll
      for (int r = 0; r < 4; ++r) {
        int i = i0 + (wm * 2 + ms) * 16 + lr * 4 + r;
        int j = j0 + (wn * 2 + ns) * 16 + lc;
        float o = acc[ms][ns][r] * scale;
        if (ACT == 3) {
          if (blockIdx.x < 8) o *= 0.18033688011112042f;  // 0.125*log2(e)
          if (blockIdx.x >= 24) {
            o += bias[j & 511];
            o = 1.0f / (1.0f + __expf(-o));
          }
        } else {
          if (bias) o += bias[j];
          if (ACT == 1) {
            o = 1.0f / (1.0f + __expf(-o));
          } else if (ACT == 2) {
            float xx = o;
            float c = 0.7978845608028654f * (xx + 0.044715f * xx * xx * xx);
            o = 0.5f * xx * (1.0f + tanhf(c));
          }
          if (res) o += res[(size_t)i * ldc + j];
        }
        if (OBF)
          ((ushort_t*)Cp)[(size_t)i * ldc + j] = f2b(o);
        else
          ((float*)Cp)[(size_t)i * ldc + j] = o;
      }
    }
  }
}

// ---------------- fused attention (swapped-operand flash, 2 passes) -------
// grid (NT/32, NH). 4 waves: ig=w&1 (16-row group), jh=w>>1 (j-half).
__device__ __forceinline__ float rq_sel(const unsigned int* rqt,
                                        unsigned int idx) {
  unsigned int d01 = (idx & 2) ? rqt[1] : rqt[0];
  unsigned int d23 = (idx & 2) ? rqt[3] : rqt[2];
  unsigned int dd = (idx & 4) ? d23 : d01;
  unsigned int r = (idx & 1) ? (dd & 0xffff0000u) : (dd << 16);
  return __uint_as_float(r);
}

__global__ __launch_bounds__(256) void attn_kernel(
    const ushort_t* __restrict__ xqkvg, const ushort_t* __restrict__ vbT,
    const float* __restrict__ relk, const uchar_t* __restrict__ adm8,
    float* __restrict__ att, ushort_t* __restrict__ av) {
  int h = blockIdx.y;
  int i0 = blockIdx.x * 32;
  int t = threadIdx.x, w = t >> 6, l = t & 63;
  int lr = l >> 4, lc = l & 15;
  int ig = w & 1, jh = w >> 1;
  int i_loc = ig * 16 + lc;
  int i = i0 + i_loc;

  __shared__ __align__(16) ushort_t Ks[2][4096];
  __shared__ __align__(16) ushort_t Vs[2][4096];
  __shared__ __align__(16) ushort_t Ps[2][2048];
  __shared__ float Od[32][68];
  __shared__ float MLs[2][2][16][2];

  // Q b-frags (k 0..31, 32..63)
  const ushort_t* qp = xqkvg + (size_t)i * QS + h * 64 + lr * 8;
  s8x qf0 = *(const s8x*)qp;
  s8x qf1 = *(const s8x*)(qp + 32);

  // rq table: rq[p] = q_i . rel_k[p]  (in-register, shfl-reduced)
  unsigned int rqt[4];
  {
    const ushort_t* q0 = (const ushort_t*)&qf0;
    const ushort_t* q1 = (const ushort_t*)&qf1;
    float sp[8];
#pragma unroll
    for (int p = 0; p < 8; ++p) {
      const float* rp = relk + p * 64 + lr * 8;
      float s = 0.f;
#pragma unroll
      for (int e = 0; e < 8; ++e) s = fmaf(b2f(q0[e]), rp[e], s);
#pragma unroll
      for (int e = 0; e < 8; ++e) s = fmaf(b2f(q1[e]), rp[32 + e], s);
      s += __shfl_xor(s, 16);
      s += __shfl_xor(s, 32);
      sp[p] = s;
    }
#pragma unroll
    for (int j = 0; j < 4; ++j)
      rqt[j] = (unsigned int)f2b(sp[2 * j]) |
               ((unsigned int)f2b(sp[2 * j + 1]) << 16);
  }

  // staging geometry
  int stgo = (w & 1) * 2048;  // this wave's half of an 8KB tile (ushort idx)
  int srow = (w & 1) * 32 + (l >> 3);
  int kp8 = ((l & 7) ^ (l >> 3)) * 8;
  ushort_t* KS = Ks[jh];
  ushort_t* VS = Vs[jh];
  ushort_t* PS = Ps[jh];
  const ushort_t* kSrc0 =
      xqkvg + 512 + (size_t)(jh * 64 + srow) * QS + h * 64 + kp8;
  const ushort_t* vSrc0 = vbT + (size_t)(h * 64 + srow) * NT + jh * 64 + kp8;
  const uchar_t* admp0 = adm8 + (size_t)i * NT + jh * 64 + lr * 4;

  // fragment read offsets (ushort idx), XOR-swizzled
  int sw = (lc & 7);
  int a_b0 = lc * 64 + ((lr ^ sw) << 3);
  int a_b1 = lc * 64 + (((4 + lr) ^ sw) << 3);
  int pb0 = i_loc * 64 + ((lr ^ sw) << 3);
  int pb1 = i_loc * 64 + (((4 + lr) ^ sw) << 3);
  int swz8 = sw << 3;

  float m_run = -1e30f, l_run = 0.f;

  // ================= pass 1: running max/sum =================
  {
    const ushort_t* kSrc = kSrc0;
    const uchar_t* admp = admp0;
    for (int tt = 0; tt < 24; ++tt) {
#pragma unroll
      for (int q = 0; q < 4; ++q)
        gload16(kSrc + (size_t)q * 8 * QS, KS + stgo + q * 512);
      __syncthreads();
      fx4 sacc[4] = {};
#pragma unroll
      for (int ja = 0; ja < 4; ++ja) {
        s8x a0 = *(const s8x*)(KS + a_b0 + ja * 1024);
        s8x a1 = *(const s8x*)(KS + a_b1 + ja * 1024);
        sacc[ja] = MFMA(a0, qf0, sacc[ja]);
        sacc[ja] = MFMA(a1, qf1, sacc[ja]);
      }
      float sv[4][4];
      float tm = -1e30f;
#pragma unroll
      for (int ja = 0; ja < 4; ++ja) {
        unsigned int aw = *(const unsigned int*)(admp + ja * 16);
#pragma unroll
        for (int r = 0; r < 4; ++r) {
          float vv = sacc[ja][r] + rq_sel(rqt, (aw >> (8 * r)) & 7u);
          sv[ja][r] = vv;
          tm = fmaxf(tm, vv);
        }
      }
      float mn = fmaxf(m_run, tm);
      float sum = 0.f;
#pragma unroll
      for (int ja = 0; ja < 4; ++ja)
#pragma unroll
        for (int r = 0; r < 4; ++r) sum += EX2(sv[ja][r] - mn);
      l_run = l_run * EX2(m_run - mn) + sum;
      m_run = mn;
      kSrc += (size_t)128 * QS;
      admp += 128;
      __syncthreads();
    }
  }
  // merge across lanes (row i spread over lr copies)
#pragma unroll
  for (int off = 16; off <= 32; off <<= 1) {
    float mo = __shfl_xor(m_run, off), lo = __shfl_xor(l_run, off);
    float mn = fmaxf(m_run, mo);
    l_run = l_run * EX2(m_run - mn) + lo * EX2(mo - mn);
    m_run = mn;
  }
  if (l < 16) {
    MLs[jh][ig][lc][0] = m_run;
    MLs[jh][ig][lc][1] = l_run;
  }
  __syncthreads();
  {
    float mo = MLs[jh ^ 1][ig][lc][0], lo = MLs[jh ^ 1][ig][lc][1];
    float mn = fmaxf(m_run, mo);
    l_run = l_run * EX2(m_run - mn) + lo * EX2(mo - mn);
    m_run = mn;
  }
  float lofs = m_run + __log2f(l_run);
  __syncthreads();

  // ================= pass 2: P write + PV =================
  fx4 oacc[4] = {};
  float* attb = att + ((size_t)h * NT + i0) * NT;
  int jh64 = jh * 64;
  {
    const ushort_t* kSrc = kSrc0;
    const ushort_t* vSrc = vSrc0;
    const uchar_t* admp = admp0;
    for (int tt = 0; tt < 24; ++tt) {
#pragma unroll
      for (int q = 0; q < 4; ++q) {
        gload16(kSrc + (size_t)q * 8 * QS, KS + stgo + q * 512);
        gload16(vSrc + (size_t)q * 8 * NT, VS + stgo + q * 512);
      }
      __syncthreads();
      fx4 sacc[4] = {};
#pragma unroll
      for (int ja = 0; ja < 4; ++ja) {
        s8x a0 = *(const s8x*)(KS + a_b0 + ja * 1024);
        s8x a1 = *(const s8x*)(KS + a_b1 + ja * 1024);
        sacc[ja] = MFMA(a0, qf0, sacc[ja]);
        sacc[ja] = MFMA(a1, qf1, sacc[ja]);
      }
#pragma unroll
      for (int ja = 0; ja < 4; ++ja) {
        unsigned int aw = *(const unsigned int*)(admp + ja * 16);
        float p0 = EX2(sacc[ja][0] + rq_sel(rqt, aw & 7u) - lofs);
        float p1 = EX2(sacc[ja][1] + rq_sel(rqt, (aw >> 8) & 7u) - lofs);
        float p2 = EX2(sacc[ja][2] + rq_sel(rqt, (aw >> 16) & 7u) - lofs);
        float p3 = EX2(sacc[ja][3] + rq_sel(rqt, (aw >> 24) & 7u) - lofs);
        unsigned int w01 =
            (unsigned int)f2b(p0) | ((unsigned int)f2b(p1) << 16);
        unsigned int w23 =
            (unsigned int)f2b(p2) | ((unsigned int)f2b(p3) << 16);
        int cb = ja * 16 + lr * 4;
        *(unsigned int*)&PS[i_loc * 64 + (cb ^ swz8)] = w01;
        *(unsigned int*)&PS[i_loc * 64 + ((cb + 2) ^ swz8)] = w23;
      }
      __syncthreads();
      // PV: Ot[d][i] += Vt[d][j] * P[i][j]
#pragma unroll
      for (int ks = 0; ks < 2; ++ks) {
        s8x pf = *(const s8x*)(PS + (ks == 0 ? pb0 : pb1));
#pragma unroll
        for (int nd = 0; nd < 4; ++nd) {
          s8x vf = *(const s8x*)(VS + (ks == 0 ? a_b0 : a_b1) + nd * 1024);
          oacc[nd] = MFMA(vf, pf, oacc[nd]);
        }
      }
      // coalesced att copy-out (128 threads of this jh cover 32 rows)
      {
        int uu = (w & 1) * 64 + l;
        int row = uu >> 2, cs = (uu & 3) * 16;
        int rsw = (row & 7) << 3;
        uint4 A_ = *(const uint4*)&PS[row * 64 + (cs ^ rsw)];
        uint4 B_ = *(const uint4*)&PS[row * 64 + ((cs + 8) ^ rsw)];
        const ushort_t* ap = (const ushort_t*)&A_;
        const ushort_t* bp = (const ushort_t*)&B_;
        float* op = attb + (size_t)row * NT + tt * 128 + jh64 + cs;
        f4 o0 = {b2f(ap[0]), b2f(ap[1]), b2f(ap[2]), b2f(ap[3])};
        f4 o1 = {b2f(ap[4]), b2f(ap[5]), b2f(ap[6]), b2f(ap[7])};
        f4 o2 = {b2f(bp[0]), b2f(bp[1]), b2f(bp[2]), b2f(bp[3])};
        f4 o3 = {b2f(bp[4]), b2f(bp[5]), b2f(bp[6]), b2f(bp[7])};
        *(f4*)(op + 0) = o0;
        *(f4*)(op + 4) = o1;
        *(f4*)(op + 8) = o2;
        *(f4*)(op + 12) = o3;
      }
      kSrc += (size_t)128 * QS;
      vSrc += 128;
      admp += 128;
      __syncthreads();
    }
  }
  // merge O across j-halves, write av
  if (jh == 1) {
#pragma unroll
    for (int nd = 0; nd < 4; ++nd)
#pragma unroll
      for (int r = 0; r < 4; ++r) Od[i_loc][nd * 16 + lr * 4 + r] = oacc[nd][r];
  }
  __syncthreads();
  if (jh == 0) {
#pragma unroll
    for (int nd = 0; nd < 4; ++nd)
#pragma unroll
      for (int r = 0; r < 4; ++r)
        Od[i_loc][nd * 16 + lr * 4 + r] += oacc[nd][r];
  }
  __syncthreads();
  {
    int row = t >> 3, ds = (t & 7) * 8;
    f4 oA = *(const f4*)&Od[row][ds];
    f4 oB = *(const f4*)&Od[row][ds + 4];
    ushort_t tmp[8] = {f2b(oA.x), f2b(oA.y), f2b(oA.z), f2b(oA.w),
                       f2b(oB.x), f2b(oB.y), f2b(oB.z), f2b(oB.w)};
    *(uint4*)&av[(size_t)(i0 + row) * DIM + h * 64 + ds] = *(uint4*)tmp;
  }
}

extern "C" void kernel_launch(void* const* d_in, const int* in_sizes, int n_in,
                              void* d_out, int out_size, void* d_ws,
                              size_t ws_size, hipStream_t stream) {
  const float* x_in = (const float*)d_in[0];
  const int* adm = (const int*)d_in[1];
  const float* ln_att_s = (const float*)d_in[2];
  const float* ln_att_b = (const float*)d_in[3];
  const float* Wq = (const float*)d_in[4];
  const float* Wk = (const float*)d_in[5];
  const float* Wv = (const float*)d_in[6];
  const float* rel_k = (const float*)d_in[7];
  const float* Wg = (const float*)d_in[8];
  const float* bg = (const float*)d_in[9];
  const float* Wo = (const float*)d_in[10];
  const float* bo = (const float*)d_in[11];
  const float* ln_ff_s = (const float*)d_in[12];
  const float* ln_ff_b = (const float*)d_in[13];
  const float* W1 = (const float*)d_in[14];
  const float* b1 = (const float*)d_in[15];
  const float* W2 = (const float*)d_in[16];
  const float* b2 = (const float*)d_in[17];
  float* out = (float*)d_out;

  const size_t ND = (size_t)NT * DIM;
  char* ws = (char*)d_ws;
  float* x_cur = (float*)ws;                    // 6.29 MB
  float* y = (float*)(ws + 6291456);            // 6.29 MB
  ushort_t* xqkvg = (ushort_t*)(ws + 12582912); // 12.58 MB [3072][2048]
  ushort_t* avb = (ushort_t*)(ws + 25165824);   // 3.15 MB
  ushort_t* xnb = (ushort_t*)(ws + 28311552);   // 3.15 MB
  ushort_t* vbT = (ushort_t*)(ws + 31457280);   // 3.15 MB [8][64][3072]
  uchar_t* adm8 = (uchar_t*)(ws + 34603008);    // 9.44 MB
  ushort_t* Wt = (ushort_t*)(ws + 44040192);    // 4.72 MB
  ushort_t* h1b = xqkvg;                        // FFN hidden aliases xqkvg

  hipMemcpyAsync(x_cur, x_in, ND * sizeof(float), hipMemcpyDeviceToDevice,
                 stream);
  adm8_kernel<<<(NT * NT) / 1024, 256, 0, stream>>>(adm, adm8);

  dim3 gQKVG(32, NT / 64);
  dim3 gA(8, NT / 64);
  dim3 gF1(16, NT / 64);

  for (int n = 0; n < NL; ++n) {
    float* att = out + ND + (size_t)n * NH * NT * NT;
    size_t wo = (size_t)n * DIM * DIM;

    wprep_kernel<<<576, 256, 0, stream>>>(Wq + wo, Wk + wo, Wv + wo, Wg + wo,
                                          Wo + wo, W1 + (size_t)n * DIM * D2,
                                          W2 + (size_t)n * D2 * DIM, Wt);
    ln_bf16_kernel<<<NT, 256, 0, stream>>>(x_cur, ln_att_s + n * DIM,
                                           ln_att_b + n * DIM, xnb);
    // fused QKVG: cols [0,512)=q (scaled 0.125*log2e), [512,1024)=k,
    // [1024,1536)=v, [1536,2048)=sigmoid(g + bg)
    gemm_bf16<3, true><<<gQKVG, 256, 0, stream>>>(
        xnb, nullptr, 0, Wt, bg + n * DIM, nullptr, xqkvg, DIM, QS, 1.0f);
    vt_kernel<<<dim3(NT / 64, NH), 256, 0, stream>>>(xqkvg + 1024, vbT);
    attn_kernel<<<dim3(NT / 32, NH), 256, 0, stream>>>(
        xqkvg, vbT, rel_k + n * PKN * DKH, adm8, att, avb);
    // y = x + (av*gate)@Wo + bo
    gemm_bf16<0, false><<<gA, 256, 0, stream>>>(
        avb, xqkvg + 1536, QS, Wt + 1048576, bo + n * DIM, x_cur, y, DIM, DIM,
        1.0f);
    ln_bf16_kernel<<<NT, 256, 0, stream>>>(y, ln_ff_s + n * DIM,
                                           ln_ff_b + n * DIM, xnb);
    gemm_bf16<2, true><<<gF1, 256, 0, stream>>>(xnb, nullptr, 0, Wt + 1310720,
                                                b1 + n * D2, nullptr, h1b, DIM,
                                                D2, 1.0f);
    gemm_bf16<0, false><<<gA, 256, 0, stream>>>(h1b, nullptr, 0, Wt + 1835008,
                                                b2 + n * DIM, x_cur, x_cur, D2,
                                                DIM, 1.0f);
  }
  hipMemcpyAsync(out, x_cur, ND * sizeof(float), hipMemcpyDeviceToDevice,
                 stream);
}

// Round 4
// 1057.249 us; speedup vs baseline: 2.4813x; 1.0753x over previous
//
#include <hip/hip_runtime.h>
#include <math.h>

#define NT 3072
#define DIM 512
#define NH 8
#define DKH 64
#define PKN 8
#define D2 1024
#define NL 3
#define QS 2048  // row stride of fused qkvg buffer

typedef float4 f4;
typedef unsigned short ushort_t;
typedef unsigned char uchar_t;
typedef __attribute__((ext_vector_type(8))) short s8x;
typedef __attribute__((ext_vector_type(4))) float fx4;

#define MFMA(a, b, c) __builtin_amdgcn_mfma_f32_16x16x32_bf16(a, b, c, 0, 0, 0)
#define EX2(x) __builtin_amdgcn_exp2f(x)

__device__ __forceinline__ float b2f(ushort_t u) {
  union { unsigned int x; float f; } c;
  c.x = (unsigned int)u << 16;
  return c.f;
}
__device__ __forceinline__ ushort_t f2b(float f) {
  union { float f; unsigned int x; } c;
  c.f = f;
  unsigned int r = (c.x + 0x7FFFu + ((c.x >> 16) & 1u)) >> 16;
  return (ushort_t)r;
}
__device__ __forceinline__ float wred_sum(float v) {
#pragma unroll
  for (int off = 32; off > 0; off >>= 1) v += __shfl_xor(v, off);
  return v;
}
__device__ __forceinline__ void gload16(const ushort_t* g, ushort_t* l) {
  __builtin_amdgcn_global_load_lds(
      (const __attribute__((address_space(1))) unsigned int*)(const void*)g,
      (__attribute__((address_space(3))) unsigned int*)(void*)l, 16, 0, 0);
}

// ---------------- LayerNorm -> bf16 ----------------
__global__ __launch_bounds__(256) void ln_bf16_kernel(
    const float* __restrict__ x, const float* __restrict__ s,
    const float* __restrict__ b, ushort_t* __restrict__ out) {
  int row = blockIdx.x;
  const float* xr = x + (size_t)row * DIM;
  int t = threadIdx.x;
  float v0 = xr[t], v1 = xr[t + 256];
  float sum = wred_sum(v0 + v1);
  float sq = wred_sum(v0 * v0 + v1 * v1);
  __shared__ float ss[4], s2[4];
  if ((t & 63) == 0) { ss[t >> 6] = sum; s2[t >> 6] = sq; }
  __syncthreads();
  float tot = ss[0] + ss[1] + ss[2] + ss[3];
  float tot2 = s2[0] + s2[1] + s2[2] + s2[3];
  float mean = tot * (1.0f / DIM);
  float var = tot2 * (1.0f / DIM) - mean * mean;
  float inv = rsqrtf(var + 1e-6f);
  ushort_t* orow = out + (size_t)row * DIM;
  orow[t] = f2b((v0 - mean) * inv * s[t] + b[t]);
  orow[t + 256] = f2b((v1 - mean) * inv * s[t + 256] + b[t + 256]);
}

// ---------------- fused per-layer weight transpose+convert -------------
__device__ __forceinline__ void tconv_body(const float* __restrict__ W,
                                           ushort_t* __restrict__ Wt, int K,
                                           int Nc, int tx, int ty) {
  __shared__ float Ls[64][65];
  int t = threadIdx.x;
  int n0 = tx * 64, k0 = ty * 64;
  int rr = t >> 4, cc = (t & 15) * 4;
#pragma unroll
  for (int p = 0; p < 4; ++p) {
    f4 v = *(const f4*)&W[(size_t)(k0 + rr + p * 16) * Nc + n0 + cc];
    Ls[rr + p * 16][cc + 0] = v.x;
    Ls[rr + p * 16][cc + 1] = v.y;
    Ls[rr + p * 16][cc + 2] = v.z;
    Ls[rr + p * 16][cc + 3] = v.w;
  }
  __syncthreads();
  int nr = t >> 2, kc = (t & 3) * 16;
  ushort_t tmp[16];
#pragma unroll
  for (int e = 0; e < 16; ++e) tmp[e] = f2b(Ls[kc + e][nr]);
  ushort_t* dst = &Wt[(size_t)(n0 + nr) * K + k0 + kc];
  *(uint4*)dst = *(uint4*)&tmp[0];
  *(uint4*)(dst + 8) = *(uint4*)&tmp[8];
}

__global__ __launch_bounds__(256) void wprep_kernel(
    const float* __restrict__ Wq, const float* __restrict__ Wk,
    const float* __restrict__ Wv, const float* __restrict__ Wg,
    const float* __restrict__ Wo, const float* __restrict__ W1,
    const float* __restrict__ W2, ushort_t* __restrict__ Wt) {
  int bid = blockIdx.x;
  if (bid < 320) {
    int job = bid >> 6, tile = bid & 63;
    const float* src = job == 0 ? Wq : job == 1 ? Wk : job == 2 ? Wv
                       : job == 3 ? Wg : Wo;
    tconv_body(src, Wt + (size_t)job * 262144, 512, 512, tile & 7, tile >> 3);
  } else if (bid < 448) {
    int tile = bid - 320;
    tconv_body(W1, Wt + 1310720, 512, 1024, tile & 15, tile >> 4);
  } else {
    int tile = bid - 448;
    tconv_body(W2, Wt + 1835008, 1024, 512, tile & 7, tile >> 3);
  }
}

// ---------------- adm int32 -> int8 ----------------
__global__ __launch_bounds__(256) void adm8_kernel(const int* __restrict__ adm,
                                                   uchar_t* __restrict__ out) {
  size_t i = ((size_t)blockIdx.x * 256 + threadIdx.x) * 4;
  int4 v = *(const int4*)&adm[i];
  unsigned int b = (unsigned)(v.x & 255) | ((unsigned)(v.y & 255) << 8) |
                   ((unsigned)(v.z & 255) << 16) | ((unsigned)(v.w & 255) << 24);
  *(unsigned int*)&out[i] = b;
}

// ---------------- V transpose per head: vbT[h][d][j] = v[j][h*64+d] ------
__global__ __launch_bounds__(256) void vt_kernel(const ushort_t* __restrict__ v,
                                                 ushort_t* __restrict__ vbT) {
  int jt = blockIdx.x, h = blockIdx.y;
  __shared__ ushort_t L[64][72];
  int t = threadIdx.x;
  int r = t >> 2, c = (t & 3) * 16;
  const ushort_t* src = v + (size_t)(jt * 64 + r) * QS + h * 64 + c;
  *(uint4*)&L[r][c] = *(const uint4*)src;
  *(uint4*)&L[r][c + 8] = *(const uint4*)(src + 8);
  __syncthreads();
  int d = t >> 2, j0 = (t & 3) * 16;
  ushort_t tmp[16];
#pragma unroll
  for (int e = 0; e < 16; ++e) tmp[e] = L[j0 + e][d];
  ushort_t* dst = vbT + (size_t)(h * 64 + d) * NT + jt * 64 + j0;
  *(uint4*)dst = *(uint4*)&tmp[0];
  *(uint4*)(dst + 8) = *(uint4*)&tmp[8];
}

// ---------------- bf16 MFMA GEMM, 64x64 tile, BK=64, dbuf + gload_lds ----
// ACT: 0 none, 1 sigmoid, 2 gelu(tanh), 3 fused-QKVG epilogue
template <int ACT, bool OBF>
__global__ __launch_bounds__(256) void gemm64(
    const ushort_t* __restrict__ A, const ushort_t* __restrict__ Bt,
    const float* __restrict__ bias, const float* __restrict__ res,
    void* __restrict__ Cp, int K, int ldc, float scale) {
  __shared__ __align__(16) ushort_t As[2][4096];
  __shared__ __align__(16) ushort_t Bs[2][4096];
  int t = threadIdx.x;
  int i0 = blockIdx.y * 64, j0 = blockIdx.x * 64;
  int w = t >> 6, l = t & 63;
  int wm = w >> 1, wn = w & 1;
  int lr = l >> 4, lc = l & 15;
  // staging map: thread t -> row sr (+32 for q=1), 16B chunk (t&7), swizzled src
  int sr = t >> 3;
  int sc8 = ((t & 7) ^ (sr & 7)) * 8;
  const ushort_t* aS = A + (size_t)(i0 + sr) * K + sc8;
  const ushort_t* bS = Bt + (size_t)(j0 + sr) * K + sc8;
  // frag read offsets (ushort idx): row*64 + ((chunk ^ (row&7))*8), chunk=ks*4+lr
  int sA0 = (wm * 32 + lc) * 64 + ((lr ^ (lc & 7)) * 8);
  int sA1 = (wm * 32 + 16 + lc) * 64 + ((lr ^ (lc & 7)) * 8);
  int sB0 = (wn * 32 + lc) * 64 + ((lr ^ (lc & 7)) * 8);
  int sB1 = (wn * 32 + 16 + lc) * 64 + ((lr ^ (lc & 7)) * 8);

  fx4 acc[2][2] = {};

#define G64_STAGE(buf, k0)                                                   \
  {                                                                          \
    gload16(aS + (k0), &As[buf][t * 8]);                                     \
    gload16(aS + (k0) + (size_t)32 * K, &As[buf][2048 + t * 8]);             \
    gload16(bS + (k0), &Bs[buf][t * 8]);                                     \
    gload16(bS + (k0) + (size_t)32 * K, &Bs[buf][2048 + t * 8]);             \
  }

  G64_STAGE(0, 0);
  __syncthreads();
  int cur = 0;
  for (int k0 = 0; k0 < K; k0 += 64) {
    if (k0 + 64 < K) G64_STAGE(cur ^ 1, k0 + 64);
    const ushort_t* Ac = As[cur];
    const ushort_t* Bc = Bs[cur];
#pragma unroll
    for (int ks = 0; ks < 2; ++ks) {
      s8x a0 = *(const s8x*)&Ac[sA0 ^ (ks << 5)];
      s8x a1 = *(const s8x*)&Ac[sA1 ^ (ks << 5)];
      s8x b0 = *(const s8x*)&Bc[sB0 ^ (ks << 5)];
      s8x b1 = *(const s8x*)&Bc[sB1 ^ (ks << 5)];
      acc[0][0] = MFMA(a0, b0, acc[0][0]);
      acc[0][1] = MFMA(a0, b1, acc[0][1]);
      acc[1][0] = MFMA(a1, b0, acc[1][0]);
      acc[1][1] = MFMA(a1, b1, acc[1][1]);
    }
    __syncthreads();
    cur ^= 1;
  }
#undef G64_STAGE

#pragma unroll
  for (int ms = 0; ms < 2; ++ms) {
#pragma unroll
    for (int ns = 0; ns < 2; ++ns) {
#pragma unroll
      for (int r = 0; r < 4; ++r) {
        int i = i0 + wm * 32 + ms * 16 + lr * 4 + r;
        int j = j0 + wn * 32 + ns * 16 + lc;
        float o = acc[ms][ns][r] * scale;
        if (ACT == 3) {
          if (blockIdx.x < 8) o *= 0.18033688011112042f;  // 0.125*log2(e)
          if (blockIdx.x >= 24) {
            o += bias[j & 511];
            o = 1.0f / (1.0f + __expf(-o));
          }
        } else {
          if (bias) o += bias[j];
          if (ACT == 1) {
            o = 1.0f / (1.0f + __expf(-o));
          } else if (ACT == 2) {
            float xx = o;
            float c2 = 1.5957691216057308f * (xx + 0.044715f * xx * xx * xx);
            o = xx / (1.0f + __expf(-c2));  // == 0.5x(1+tanh(c))
          }
          if (res) o += res[(size_t)i * ldc + j];
        }
        if (OBF)
          ((ushort_t*)Cp)[(size_t)i * ldc + j] = f2b(o);
        else
          ((float*)Cp)[(size_t)i * ldc + j] = o;
      }
    }
  }
}

// ---------------- fused attention (swapped-operand flash, 2 passes) -------
// grid flat 768 blocks; XCD-swizzle: h = flat%8 (one head per XCD).
__device__ __forceinline__ float rq_sel(const unsigned int* rqt,
                                        unsigned int idx) {
  unsigned int d01 = (idx & 2) ? rqt[1] : rqt[0];
  unsigned int d23 = (idx & 2) ? rqt[3] : rqt[2];
  unsigned int dd = (idx & 4) ? d23 : d01;
  unsigned int r = (idx & 1) ? (dd & 0xffff0000u) : (dd << 16);
  return __uint_as_float(r);
}

__global__ __launch_bounds__(256) void attn_kernel(
    const ushort_t* __restrict__ xqkvg, const ushort_t* __restrict__ vbT,
    const float* __restrict__ relk, const uchar_t* __restrict__ adm8,
    float* __restrict__ att, ushort_t* __restrict__ av) {
  int f = blockIdx.y * (NT / 32) + blockIdx.x;
  int h = f & 7;          // head per XCD (T1 swizzle)
  int i0 = (f >> 3) * 32;
  int t = threadIdx.x, w = t >> 6, l = t & 63;
  int lr = l >> 4, lc = l & 15;
  int ig = w & 1, jh = w >> 1;
  int i_loc = ig * 16 + lc;
  int i = i0 + i_loc;

  __shared__ __align__(16) ushort_t Kd[2][2][4096];  // [buf][jh] 32KB
  __shared__ __align__(16) ushort_t Vd[2][2][4096];  // 32KB
  __shared__ __align__(16) ushort_t Ps[2][2048];     // 8KB
  __shared__ float MLs[2][2][16][2];

  // staging geometry (linear LDS dest, pre-swizzled global src)
  int stgo = ig * 2048;
  int srow = ig * 32 + (l >> 3);
  int kp8 = ((l & 7) ^ ((l >> 3) & 7)) * 8;
  const ushort_t* kSrc0 =
      xqkvg + 512 + (size_t)(jh * 64 + srow) * QS + h * 64 + kp8;
  const ushort_t* vSrc0 = vbT + (size_t)(h * 64 + srow) * NT + jh * 64 + kp8;
  const uchar_t* admp0 = adm8 + (size_t)i * NT + jh * 64 + lr * 4;

#define STAGE_K(buf, tt)                                                     \
  {                                                                          \
    const ushort_t* ks_ = kSrc0 + (size_t)(tt) * 128 * QS;                   \
    gload16(ks_, Kd[buf][jh] + stgo);                                        \
    gload16(ks_ + (size_t)8 * QS, Kd[buf][jh] + stgo + 512);                 \
    gload16(ks_ + (size_t)16 * QS, Kd[buf][jh] + stgo + 1024);               \
    gload16(ks_ + (size_t)24 * QS, Kd[buf][jh] + stgo + 1536);               \
  }
#define STAGE_V(buf, tt)                                                     \
  {                                                                          \
    const ushort_t* vs_ = vSrc0 + (tt) * 128;                                \
    gload16(vs_, Vd[buf][jh] + stgo);                                        \
    gload16(vs_ + (size_t)8 * NT, Vd[buf][jh] + stgo + 512);                 \
    gload16(vs_ + (size_t)16 * NT, Vd[buf][jh] + stgo + 1024);               \
    gload16(vs_ + (size_t)24 * NT, Vd[buf][jh] + stgo + 1536);               \
  }

  STAGE_K(0, 0);  // prologue: tile 0 in flight while rq computes

  // Q b-frags
  const ushort_t* qp = xqkvg + (size_t)i * QS + h * 64 + lr * 8;
  s8x qf0 = *(const s8x*)qp;
  s8x qf1 = *(const s8x*)(qp + 32);

  // rq table (in-register)
  unsigned int rqt[4];
  {
    const ushort_t* q0 = (const ushort_t*)&qf0;
    const ushort_t* q1 = (const ushort_t*)&qf1;
    float sp[8];
#pragma unroll
    for (int p = 0; p < 8; ++p) {
      const float* rp = relk + p * 64 + lr * 8;
      float s = 0.f;
#pragma unroll
      for (int e = 0; e < 8; ++e) s = fmaf(b2f(q0[e]), rp[e], s);
#pragma unroll
      for (int e = 0; e < 8; ++e) s = fmaf(b2f(q1[e]), rp[32 + e], s);
      s += __shfl_xor(s, 16);
      s += __shfl_xor(s, 32);
      sp[p] = s;
    }
#pragma unroll
    for (int j = 0; j < 4; ++j)
      rqt[j] = (unsigned int)f2b(sp[2 * j]) |
               ((unsigned int)f2b(sp[2 * j + 1]) << 16);
  }

  // fragment read offsets (XOR-swizzled)
  int sw = (lc & 7);
  int a_b0 = lc * 64 + ((lr ^ sw) << 3);
  int a_b1 = lc * 64 + (((4 + lr) ^ sw) << 3);
  int pb0 = i_loc * 64 + ((lr ^ sw) << 3);
  int pb1 = i_loc * 64 + (((4 + lr) ^ sw) << 3);
  int swz8 = sw << 3;

  float m_run = -1e30f, l_run = 0.f;
  __syncthreads();  // tile0 staged

  // ================= pass 1: running max/sum (dbuf, 1 barrier/tile) ======
  {
    int cur = 0;
    for (int tt = 0; tt < 24; ++tt) {
      if (tt < 23) STAGE_K(cur ^ 1, tt + 1);
      const ushort_t* KS = Kd[cur][jh];
      const uchar_t* admp = admp0 + tt * 128;
      fx4 sacc[4] = {};
#pragma unroll
      for (int ja = 0; ja < 4; ++ja) {
        s8x a0 = *(const s8x*)(KS + a_b0 + ja * 1024);
        s8x a1 = *(const s8x*)(KS + a_b1 + ja * 1024);
        sacc[ja] = MFMA(a0, qf0, sacc[ja]);
        sacc[ja] = MFMA(a1, qf1, sacc[ja]);
      }
      float sv[4][4];
      float tm = -1e30f;
#pragma unroll
      for (int ja = 0; ja < 4; ++ja) {
        unsigned int aw = *(const unsigned int*)(admp + ja * 16);
#pragma unroll
        for (int r = 0; r < 4; ++r) {
          float vv = sacc[ja][r] + rq_sel(rqt, (aw >> (8 * r)) & 7u);
          sv[ja][r] = vv;
          tm = fmaxf(tm, vv);
        }
      }
      float mn = fmaxf(m_run, tm);
      float sum = 0.f;
#pragma unroll
      for (int ja = 0; ja < 4; ++ja)
#pragma unroll
        for (int r = 0; r < 4; ++r) sum += EX2(sv[ja][r] - mn);
      l_run = l_run * EX2(m_run - mn) + sum;
      m_run = mn;
      __syncthreads();
      cur ^= 1;
    }
  }

  // prologue for pass 2 (overlap with m/l merge)
  STAGE_K(0, 0);
  STAGE_V(0, 0);

  // merge m/l across lane groups and j-halves
#pragma unroll
  for (int off = 16; off <= 32; off <<= 1) {
    float mo = __shfl_xor(m_run, off), lo = __shfl_xor(l_run, off);
    float mn = fmaxf(m_run, mo);
    l_run = l_run * EX2(m_run - mn) + lo * EX2(mo - mn);
    m_run = mn;
  }
  if (l < 16) {
    MLs[jh][ig][lc][0] = m_run;
    MLs[jh][ig][lc][1] = l_run;
  }
  __syncthreads();  // MLs + pass2 tile0 staged
  {
    float mo = MLs[jh ^ 1][ig][lc][0], lo = MLs[jh ^ 1][ig][lc][1];
    float mn = fmaxf(m_run, mo);
    l_run = l_run * EX2(m_run - mn) + lo * EX2(mo - mn);
    m_run = mn;
  }
  float lofs = m_run + __log2f(l_run);

  // ================= pass 2: P write + att out + PV (1 barrier/tile) =====
  fx4 oacc[4] = {};
  float* attb = att + ((size_t)h * NT + i0) * NT;
  ushort_t* PS = Ps[jh];
  int jh64 = jh * 64;
  {
    int cur = 0;
    for (int tt = 0; tt < 24; ++tt) {
      if (tt < 23) {
        STAGE_K(cur ^ 1, tt + 1);
        STAGE_V(cur ^ 1, tt + 1);
      }
      const ushort_t* KS = Kd[cur][jh];
      const ushort_t* VS = Vd[cur][jh];
      const uchar_t* admp = admp0 + tt * 128;
      fx4 sacc[4] = {};
#pragma unroll
      for (int ja = 0; ja < 4; ++ja) {
        s8x a0 = *(const s8x*)(KS + a_b0 + ja * 1024);
        s8x a1 = *(const s8x*)(KS + a_b1 + ja * 1024);
        sacc[ja] = MFMA(a0, qf0, sacc[ja]);
        sacc[ja] = MFMA(a1, qf1, sacc[ja]);
      }
#pragma unroll
      for (int ja = 0; ja < 4; ++ja) {
        unsigned int aw = *(const unsigned int*)(admp + ja * 16);
        float p0 = EX2(sacc[ja][0] + rq_sel(rqt, aw & 7u) - lofs);
        float p1 = EX2(sacc[ja][1] + rq_sel(rqt, (aw >> 8) & 7u) - lofs);
        float p2 = EX2(sacc[ja][2] + rq_sel(rqt, (aw >> 16) & 7u) - lofs);
        float p3 = EX2(sacc[ja][3] + rq_sel(rqt, (aw >> 24) & 7u) - lofs);
        unsigned int w01 = (unsigned int)f2b(p0) | ((unsigned int)f2b(p1) << 16);
        unsigned int w23 = (unsigned int)f2b(p2) | ((unsigned int)f2b(p3) << 16);
        int cb = ja * 16 + lr * 4;
        *(unsigned int*)&PS[i_loc * 64 + (cb ^ swz8)] = w01;
        *(unsigned int*)&PS[i_loc * 64 + ((cb + 2) ^ swz8)] = w23;
      }
      // att copy-out FIRST (same-wave LDS; stores drain under PV compute)
      {
        int uu = ig * 64 + l;
        int row = uu >> 2, cs = (uu & 3) * 16;
        int rsw = (row & 7) << 3;
        uint4 A_ = *(const uint4*)&PS[row * 64 + (cs ^ rsw)];
        uint4 B_ = *(const uint4*)&PS[row * 64 + ((cs + 8) ^ rsw)];
        const ushort_t* ap = (const ushort_t*)&A_;
        const ushort_t* bp = (const ushort_t*)&B_;
        float* op = attb + (size_t)row * NT + tt * 128 + jh64 + cs;
        f4 o0 = {b2f(ap[0]), b2f(ap[1]), b2f(ap[2]), b2f(ap[3])};
        f4 o1 = {b2f(ap[4]), b2f(ap[5]), b2f(ap[6]), b2f(ap[7])};
        f4 o2 = {b2f(bp[0]), b2f(bp[1]), b2f(bp[2]), b2f(bp[3])};
        f4 o3 = {b2f(bp[4]), b2f(bp[5]), b2f(bp[6]), b2f(bp[7])};
        *(f4*)(op + 0) = o0;
        *(f4*)(op + 4) = o1;
        *(f4*)(op + 8) = o2;
        *(f4*)(op + 12) = o3;
      }
      // PV: Ot[d][i] += Vt[d][j] * P[i][j]
#pragma unroll
      for (int ks = 0; ks < 2; ++ks) {
        s8x pf = *(const s8x*)(PS + (ks == 0 ? pb0 : pb1));
#pragma unroll
        for (int nd = 0; nd < 4; ++nd) {
          s8x vf = *(const s8x*)(VS + (ks == 0 ? a_b0 : a_b1) + nd * 1024);
          oacc[nd] = MFMA(vf, pf, oacc[nd]);
        }
      }
      __syncthreads();
      cur ^= 1;
    }
  }
#undef STAGE_K
#undef STAGE_V

  // merge O across j-halves via Ps (bf16), apply gate, write av
  ushort_t* PsF = &Ps[0][0];
  int swzO = (i_loc & 7) << 3;
  if (jh == 1) {
#pragma unroll
    for (int nd = 0; nd < 4; ++nd) {
      int d0 = nd * 16 + lr * 4;
      unsigned int lo = (unsigned int)f2b(oacc[nd][0]) |
                        ((unsigned int)f2b(oacc[nd][1]) << 16);
      unsigned int hi = (unsigned int)f2b(oacc[nd][2]) |
                        ((unsigned int)f2b(oacc[nd][3]) << 16);
      uint2 pk = {lo, hi};
      *(uint2*)&PsF[i_loc * 64 + (d0 ^ swzO)] = pk;
    }
  }
  __syncthreads();
  if (jh == 0) {
    const ushort_t* gp = xqkvg + (size_t)i * QS + 1536 + h * 64;
#pragma unroll
    for (int nd = 0; nd < 4; ++nd) {
      int d0 = nd * 16 + lr * 4;
      uint2 pk = *(const uint2*)&PsF[i_loc * 64 + (d0 ^ swzO)];
      const ushort_t* pp = (const ushort_t*)&pk;
      uint2 gk = *(const uint2*)(gp + d0);
      const ushort_t* gg = (const ushort_t*)&gk;
      ushort_t ot[4];
#pragma unroll
      for (int r = 0; r < 4; ++r)
        ot[r] = f2b((oacc[nd][r] + b2f(pp[r])) * b2f(gg[r]));
      *(uint2*)&av[(size_t)i * DIM + h * 64 + d0] = *(uint2*)ot;
    }
  }
}

extern "C" void kernel_launch(void* const* d_in, const int* in_sizes, int n_in,
                              void* d_out, int out_size, void* d_ws,
                              size_t ws_size, hipStream_t stream) {
  const float* x_in = (const float*)d_in[0];
  const int* adm = (const int*)d_in[1];
  const float* ln_att_s = (const float*)d_in[2];
  const float* ln_att_b = (const float*)d_in[3];
  const float* Wq = (const float*)d_in[4];
  const float* Wk = (const float*)d_in[5];
  const float* Wv = (const float*)d_in[6];
  const float* rel_k = (const float*)d_in[7];
  const float* Wg = (const float*)d_in[8];
  const float* bg = (const float*)d_in[9];
  const float* Wo = (const float*)d_in[10];
  const float* bo = (const float*)d_in[11];
  const float* ln_ff_s = (const float*)d_in[12];
  const float* ln_ff_b = (const float*)d_in[13];
  const float* W1 = (const float*)d_in[14];
  const float* b1 = (const float*)d_in[15];
  const float* W2 = (const float*)d_in[16];
  const float* b2 = (const float*)d_in[17];
  float* out = (float*)d_out;

  const size_t ND = (size_t)NT * DIM;
  char* ws = (char*)d_ws;
  float* x_cur = (float*)ws;                    // 6.29 MB
  float* y = (float*)(ws + 6291456);            // 6.29 MB
  ushort_t* xqkvg = (ushort_t*)(ws + 12582912); // 12.58 MB [3072][2048]
  ushort_t* avb = (ushort_t*)(ws + 25165824);   // 3.15 MB
  ushort_t* xnb = (ushort_t*)(ws + 28311552);   // 3.15 MB
  ushort_t* vbT = (ushort_t*)(ws + 31457280);   // 3.15 MB [8][64][3072]
  uchar_t* adm8 = (uchar_t*)(ws + 34603008);    // 9.44 MB
  ushort_t* Wt = (ushort_t*)(ws + 44040192);    // 4.72 MB
  ushort_t* h1b = xqkvg;                        // FFN hidden aliases xqkvg

  hipMemcpyAsync(x_cur, x_in, ND * sizeof(float), hipMemcpyDeviceToDevice,
                 stream);
  adm8_kernel<<<(NT * NT) / 1024, 256, 0, stream>>>(adm, adm8);

  dim3 gQKVG(32, NT / 64);
  dim3 gA(8, NT / 64);
  dim3 gF1(16, NT / 64);

  for (int n = 0; n < NL; ++n) {
    float* att = out + ND + (size_t)n * NH * NT * NT;
    size_t wo = (size_t)n * DIM * DIM;

    wprep_kernel<<<576, 256, 0, stream>>>(Wq + wo, Wk + wo, Wv + wo, Wg + wo,
                                          Wo + wo, W1 + (size_t)n * DIM * D2,
                                          W2 + (size_t)n * D2 * DIM, Wt);
    ln_bf16_kernel<<<NT, 256, 0, stream>>>(x_cur, ln_att_s + n * DIM,
                                           ln_att_b + n * DIM, xnb);
    // fused QKVG: cols [0,512)=q(scaled), [512,1024)=k, [1024,1536)=v,
    // [1536,2048)=sigmoid(g+bg)
    gemm64<3, true><<<gQKVG, 256, 0, stream>>>(xnb, Wt, bg + n * DIM, nullptr,
                                               xqkvg, DIM, QS, 1.0f);
    vt_kernel<<<dim3(NT / 64, NH), 256, 0, stream>>>(xqkvg + 1024, vbT);
    attn_kernel<<<dim3(NT / 32, NH), 256, 0, stream>>>(
        xqkvg, vbT, rel_k + n * PKN * DKH, adm8, att, avb);
    // y = x + (av*gate)@Wo + bo   (gate already folded into avb)
    gemm64<0, false><<<gA, 256, 0, stream>>>(avb, Wt + 1048576, bo + n * DIM,
                                             x_cur, y, DIM, DIM, 1.0f);
    ln_bf16_kernel<<<NT, 256, 0, stream>>>(y, ln_ff_s + n * DIM,
                                           ln_ff_b + n * DIM, xnb);
    gemm64<2, true><<<gF1, 256, 0, stream>>>(xnb, Wt + 1310720, b1 + n * D2,
                                             nullptr, h1b, DIM, D2, 1.0f);
    gemm64<0, false><<<gA, 256, 0, stream>>>(h1b, Wt + 1835008, b2 + n * DIM,
                                             x_cur, x_cur, D2, DIM, 1.0f);
  }
  hipMemcpyAsync(out, x_cur, ND * sizeof(float), hipMemcpyDeviceToDevice,
                 stream);
}